// Round 1
// baseline (947.482 us; speedup 1.0000x reference)
//
#include <hip/hip_runtime.h>
#include <cstdint>
#include <cstddef>

#define D_MODEL 1024
#define NH 16
#define HD 64
#define DFF 4096
#define BATCH 4
#define SEQ 2048
#define NROWS (BATCH*SEQ)

typedef uint16_t u16;
typedef __attribute__((ext_vector_type(8))) __bf16 bf16x8;
typedef __attribute__((ext_vector_type(4))) float f32x4;
typedef __attribute__((ext_vector_type(8))) u16 u16x8;
typedef __attribute__((ext_vector_type(4))) u16 u16x4;

__device__ __forceinline__ u16 f2bf(float x){
  union { float f; uint32_t u; } v; v.f = x;
  uint32_t r = v.u + 0x7fffu + ((v.u >> 16) & 1u);
  return (u16)(r >> 16);
}
__device__ __forceinline__ float bf2f(u16 h){
  union { uint32_t u; float f; } v; v.u = ((uint32_t)h) << 16; return v.f;
}
__device__ __forceinline__ void gload16(const void* g, void* l){
  __builtin_amdgcn_global_load_lds(
      (const __attribute__((address_space(1))) void*)g,
      (__attribute__((address_space(3))) void*)l, 16, 0, 0);
}

// ---------------- weight transpose: W[K][N] f32 -> WT[N][K] bf16 ----------------
__global__ __launch_bounds__(256) void k_transpose_w(const float* __restrict__ W,
                                                     u16* __restrict__ WT, int K, int N){
  __shared__ float tile[64][68];
  const int n0 = blockIdx.x*64, k0 = blockIdx.y*64;
  const int t = threadIdx.x;
  const int rr = t >> 4, cc = t & 15;
  #pragma unroll
  for (int i = 0; i < 4; ++i){
    int row = i*16 + rr;
    float4 v = *(const float4*)(W + (size_t)(k0+row)*N + n0 + cc*4);
    tile[row][cc*4+0] = v.x; tile[row][cc*4+1] = v.y;
    tile[row][cc*4+2] = v.z; tile[row][cc*4+3] = v.w;
  }
  __syncthreads();
  #pragma unroll
  for (int i = 0; i < 4; ++i){
    int nrow = i*16 + rr;
    int kc = cc*4;
    u16x4 o;
    o[0] = f2bf(tile[kc+0][nrow]);
    o[1] = f2bf(tile[kc+1][nrow]);
    o[2] = f2bf(tile[kc+2][nrow]);
    o[3] = f2bf(tile[kc+3][nrow]);
    *(u16x4*)(WT + (size_t)(n0+nrow)*K + k0 + kc) = o;
  }
}

// ---------------- RMSNorm: f32 in -> bf16 out ----------------
__global__ __launch_bounds__(256) void k_rmsnorm(const float* __restrict__ x,
                                                 const float* __restrict__ g,
                                                 u16* __restrict__ out){
  const int row = blockIdx.x; const int t = threadIdx.x;
  const float* xr = x + (size_t)row*D_MODEL;
  float4 v = *(const float4*)(xr + t*4);
  float ss = v.x*v.x + v.y*v.y + v.z*v.z + v.w*v.w;
  #pragma unroll
  for (int off = 1; off < 64; off <<= 1) ss += __shfl_xor(ss, off);
  __shared__ float wsum[4];
  if ((t & 63) == 0) wsum[t>>6] = ss;
  __syncthreads();
  float tot = wsum[0]+wsum[1]+wsum[2]+wsum[3];
  float sc = rsqrtf(tot * (1.0f/(float)D_MODEL) + 1e-6f);
  float4 gg = *(const float4*)(g + t*4);
  u16x4 o;
  o[0]=f2bf(v.x*sc*gg.x); o[1]=f2bf(v.y*sc*gg.y);
  o[2]=f2bf(v.z*sc*gg.z); o[3]=f2bf(v.w*sc*gg.w);
  *(u16x4*)(out + (size_t)row*D_MODEL + t*4) = o;
}

// ---------------- GEMM: C[M][N] = A[M][K](bf16) @ BT[N][K](bf16)^T ----------------
// MODE 0: Cb = bf16(acc)
// MODE 1: Cf = resid + acc (f32)
// MODE 2: Cb = bf16(silu(gate)*acc)
template<int MODE>
__global__ __launch_bounds__(256) void k_gemm(
    const u16* __restrict__ A, const u16* __restrict__ BT,
    u16* __restrict__ Cb, float* __restrict__ Cf,
    const float* __restrict__ resid, const u16* __restrict__ gate,
    int M, int N, int K)
{
  __shared__ __align__(16) u16 lA[128*64];
  __shared__ __align__(16) u16 lB[128*64];
  const int t = threadIdx.x;
  const int w = t >> 6, lane = t & 63, lr = lane & 15, lg = lane >> 4;
  const int wr = w >> 1, wc = w & 1;
  const int m0 = blockIdx.y * 128, n0 = blockIdx.x * 128;

  f32x4 acc[4][4];
  #pragma unroll
  for (int i=0;i<4;++i)
    #pragma unroll
    for (int j=0;j<4;++j) acc[i][j] = (f32x4){0.f,0.f,0.f,0.f};

  const int nkt = K >> 6;
  for (int kt = 0; kt < nkt; ++kt){
    __syncthreads();
    #pragma unroll
    for (int i = 0; i < 4; ++i){
      int c = i*256 + t;
      int r = c >> 3, ch = c & 7;
      gload16(A  + (size_t)(m0 + r)*K + kt*64 + ch*8, (char*)lA + i*4096 + w*1024);
      gload16(BT + (size_t)(n0 + r)*K + kt*64 + ch*8, (char*)lB + i*4096 + w*1024);
    }
    __syncthreads();
    #pragma unroll
    for (int ks = 0; ks < 2; ++ks){
      bf16x8 af[4], bfr[4];
      #pragma unroll
      for (int mi=0; mi<4; ++mi)
        af[mi] = *(const bf16x8*)(lA + (wr*64 + mi*16 + lr)*64 + ks*32 + lg*8);
      #pragma unroll
      for (int ni=0; ni<4; ++ni)
        bfr[ni] = *(const bf16x8*)(lB + (wc*64 + ni*16 + lr)*64 + ks*32 + lg*8);
      #pragma unroll
      for (int mi=0; mi<4; ++mi)
        #pragma unroll
        for (int ni=0; ni<4; ++ni)
          acc[mi][ni] = __builtin_amdgcn_mfma_f32_16x16x32_bf16(af[mi], bfr[ni], acc[mi][ni], 0,0,0);
    }
  }
  #pragma unroll
  for (int mi=0; mi<4; ++mi){
    #pragma unroll
    for (int ni=0; ni<4; ++ni){
      int mbase = m0 + wr*64 + mi*16 + lg*4;
      int n = n0 + wc*64 + ni*16 + lr;
      #pragma unroll
      for (int r=0;r<4;++r){
        size_t idx = (size_t)(mbase + r)*N + n;
        float vv = acc[mi][ni][r];
        if (MODE == 0) Cb[idx] = f2bf(vv);
        else if (MODE == 1) Cf[idx] = resid[idx] + vv;
        else { float gt = bf2f(gate[idx]); float sg = gt / (1.f + __expf(-gt)); Cb[idx] = f2bf(sg * vv); }
      }
    }
  }
}

// ---------------- RoPE in-place on q,k (bf16) ----------------
__global__ __launch_bounds__(256) void k_rope(u16* __restrict__ q, u16* __restrict__ k,
                                              const float* __restrict__ cs,
                                              const float* __restrict__ sn){
  int tid = blockIdx.x*256 + threadIdx.x;
  int d = tid & 31, h = (tid >> 5) & 15, s = (tid >> 9) & 2047, b = tid >> 20;
  size_t base = ((size_t)(b*SEQ + s))*D_MODEL + h*HD;
  float c1 = cs[s*HD + d],      s1 = sn[s*HD + d];
  float c2 = cs[s*HD + d + 32], s2 = sn[s*HD + d + 32];
  float q1 = bf2f(q[base+d]), q2 = bf2f(q[base+d+32]);
  q[base+d]    = f2bf(q1*c1 - q2*s1);
  q[base+d+32] = f2bf(q2*c2 + q1*s2);
  float k1 = bf2f(k[base+d]), k2 = bf2f(k[base+d+32]);
  k[base+d]    = f2bf(k1*c1 - k2*s1);
  k[base+d+32] = f2bf(k2*c2 + k1*s2);
}

// ---------------- V transpose: v[B*S][D] slice -> vt[(b*16+h)*64+d][S] ----------------
__global__ __launch_bounds__(256) void k_transpose_v(const u16* __restrict__ v,
                                                     u16* __restrict__ vt){
  const int s0 = blockIdx.x*64; const int bh = blockIdx.y;
  const int b = bh >> 4, h = bh & 15;
  __shared__ u16 tile[64][72];
  const int t = threadIdx.x;
  #pragma unroll
  for (int i=0;i<2;++i){
    int c = i*256 + t;
    int sr = c >> 3, ch = c & 7;
    u16x8 vv = *(const u16x8*)(v + (size_t)(b*SEQ + s0 + sr)*D_MODEL + h*HD + ch*8);
    #pragma unroll
    for (int j=0;j<8;++j) tile[sr][ch*8+j] = vv[j];
  }
  __syncthreads();
  #pragma unroll
  for (int i=0;i<2;++i){
    int c = i*256 + t;
    int dr = c >> 3, ch = c & 7;
    u16x8 o;
    #pragma unroll
    for (int j=0;j<8;++j) o[j] = tile[ch*8+j][dr];
    *(u16x8*)(vt + (size_t)(bh*HD + dr)*SEQ + s0 + ch*8) = o;
  }
}

// ---------------- causal flash attention ----------------
// grid: (S/64, B*NH); block 256 (4 waves x 16 q-rows). KV tiles of 32.
__global__ __launch_bounds__(256) void k_attn(const u16* __restrict__ q,
                                              const u16* __restrict__ k,
                                              const u16* __restrict__ vt,
                                              u16* __restrict__ ctx){
  const int qt = blockIdx.x, bh = blockIdx.y;
  const int b = bh >> 4, h = bh & 15;
  const int t = threadIdx.x, w = t >> 6, lane = t & 63, lr = lane & 15, lg = lane >> 4;
  __shared__ __align__(16) u16 kld[32*64];   // [kk][d]
  __shared__ __align__(16) u16 vld[64*32];   // [d][kk]
  __shared__ __align__(16) u16 pld[4][16*32];

  const int qrow = qt*64 + w*16 + lr;
  const u16* qbase = q + (size_t)(b*SEQ + qrow)*D_MODEL + h*HD;
  bf16x8 qa0 = *(const bf16x8*)(qbase + lg*8);
  bf16x8 qa1 = *(const bf16x8*)(qbase + 32 + lg*8);

  float mreg[4], lreg[4]; f32x4 o[4];
  #pragma unroll
  for (int r=0;r<4;++r){ mreg[r] = -INFINITY; lreg[r] = 0.f; }
  #pragma unroll
  for (int g=0;g<4;++g) o[g] = (f32x4){0.f,0.f,0.f,0.f};

  const int wmax = qt*64 + w*16 + 15;
  const int ntiles = qt*2 + 2;
  for (int it = 0; it < ntiles; ++it){
    const int kv0 = it*32;
    __syncthreads();
    { int kk = t >> 3, ch = t & 7;
      gload16(k + (size_t)(b*SEQ + kv0 + kk)*D_MODEL + h*HD + ch*8, (char*)kld + w*1024); }
    { int d = t >> 2, ch = t & 3;
      gload16(vt + (size_t)(bh*HD + d)*SEQ + kv0 + ch*8, (char*)vld + w*1024); }
    __syncthreads();
    if (kv0 <= wmax){
      f32x4 s0 = {0.f,0.f,0.f,0.f}, s1v = {0.f,0.f,0.f,0.f};
      bf16x8 kf;
      kf = *(const bf16x8*)(kld + (lr)*64      + lg*8); s0  = __builtin_amdgcn_mfma_f32_16x16x32_bf16(qa0, kf, s0, 0,0,0);
      kf = *(const bf16x8*)(kld + (lr)*64 + 32 + lg*8); s0  = __builtin_amdgcn_mfma_f32_16x16x32_bf16(qa1, kf, s0, 0,0,0);
      kf = *(const bf16x8*)(kld + (16+lr)*64      + lg*8); s1v = __builtin_amdgcn_mfma_f32_16x16x32_bf16(qa0, kf, s1v, 0,0,0);
      kf = *(const bf16x8*)(kld + (16+lr)*64 + 32 + lg*8); s1v = __builtin_amdgcn_mfma_f32_16x16x32_bf16(qa1, kf, s1v, 0,0,0);
      float p0[4], p1[4];
      #pragma unroll
      for (int r=0;r<4;++r){
        int qg = qt*64 + w*16 + lg*4 + r;
        float v0 = s0[r]*0.125f;  if (kv0 + lr > qg)      v0 = -INFINITY;
        float v1 = s1v[r]*0.125f; if (kv0 + 16 + lr > qg) v1 = -INFINITY;
        p0[r] = v0; p1[r] = v1;
      }
      float rm[4];
      #pragma unroll
      for (int r=0;r<4;++r) rm[r] = fmaxf(p0[r], p1[r]);
      #pragma unroll
      for (int off=1; off<16; off<<=1)
        #pragma unroll
        for (int r=0;r<4;++r) rm[r] = fmaxf(rm[r], __shfl_xor(rm[r], off));
      float alpha[4];
      #pragma unroll
      for (int r=0;r<4;++r){
        float mn = fmaxf(mreg[r], rm[r]);
        alpha[r] = __expf(mreg[r] - mn);
        mreg[r] = mn;
        p0[r] = __expf(p0[r] - mn);
        p1[r] = __expf(p1[r] - mn);
      }
      float ps[4];
      #pragma unroll
      for (int r=0;r<4;++r) ps[r] = p0[r] + p1[r];
      #pragma unroll
      for (int off=1; off<16; off<<=1)
        #pragma unroll
        for (int r=0;r<4;++r) ps[r] += __shfl_xor(ps[r], off);
      #pragma unroll
      for (int r=0;r<4;++r) lreg[r] = lreg[r]*alpha[r] + ps[r];
      #pragma unroll
      for (int g=0; g<4; ++g)
        #pragma unroll
        for (int r=0;r<4;++r) o[g][r] *= alpha[r];
      #pragma unroll
      for (int r=0;r<4;++r){
        pld[w][(lg*4+r)*32 + lr]      = f2bf(p0[r]);
        pld[w][(lg*4+r)*32 + 16 + lr] = f2bf(p1[r]);
      }
      bf16x8 pa = *(const bf16x8*)(&pld[w][lr*32 + lg*8]);
      #pragma unroll
      for (int g=0; g<4; ++g){
        bf16x8 vf = *(const bf16x8*)(vld + (g*16+lr)*32 + lg*8);
        o[g] = __builtin_amdgcn_mfma_f32_16x16x32_bf16(pa, vf, o[g], 0,0,0);
      }
    }
  }
  #pragma unroll
  for (int g=0; g<4; ++g){
    int col = h*HD + g*16 + lr;
    #pragma unroll
    for (int r=0;r<4;++r){
      int row = qt*64 + w*16 + lg*4 + r;
      ctx[(size_t)(b*SEQ + row)*D_MODEL + col] = f2bf(o[g][r] / lreg[r]);
    }
  }
}

extern "C" void kernel_launch(void* const* d_in, const int* in_sizes, int n_in,
                              void* d_out, int out_size, void* d_ws, size_t ws_size,
                              hipStream_t stream){
  const float* x  = (const float*)d_in[0];
  const float* rc = (const float*)d_in[1];
  const float* rs = (const float*)d_in[2];
  const float* g1 = (const float*)d_in[3];
  const float* g2 = (const float*)d_in[4];
  const float* wq = (const float*)d_in[5];
  const float* wk = (const float*)d_in[6];
  const float* wv = (const float*)d_in[7];
  const float* wo = (const float*)d_in[8];
  const float* wg = (const float*)d_in[9];
  const float* wu = (const float*)d_in[10];
  const float* wd = (const float*)d_in[11];
  float* out = (float*)d_out;

  char* ws = (char*)d_ws;
  const size_t MB = 1024*1024;
  u16* wqT = (u16*)(ws + 0);
  u16* wkT = (u16*)(ws + 2*MB);
  u16* wvT = (u16*)(ws + 4*MB);
  u16* woT = (u16*)(ws + 6*MB);
  u16* wgT = (u16*)(ws + 8*MB);
  u16* wuT = (u16*)(ws + 16*MB);
  u16* wdT = (u16*)(ws + 24*MB);
  float* x1 = (float*)(ws + 32*MB);
  u16* xn  = (u16*)(ws + 64*MB);    // reused as ctx after QKV GEMMs
  u16* qb  = (u16*)(ws + 80*MB);
  u16* kb  = (u16*)(ws + 96*MB);
  u16* vb  = (u16*)(ws + 112*MB);   // reused as xn2 after V-transpose
  u16* vtb = (u16*)(ws + 128*MB);
  u16* gb  = (u16*)(ws + 144*MB);   // 64MB; gate then h in-place

  dim3 blk(256);
  k_transpose_w<<<dim3(16,16),blk,0,stream>>>(wq, wqT, 1024, 1024);
  k_transpose_w<<<dim3(16,16),blk,0,stream>>>(wk, wkT, 1024, 1024);
  k_transpose_w<<<dim3(16,16),blk,0,stream>>>(wv, wvT, 1024, 1024);
  k_transpose_w<<<dim3(16,16),blk,0,stream>>>(wo, woT, 1024, 1024);
  k_transpose_w<<<dim3(64,16),blk,0,stream>>>(wg, wgT, 1024, 4096);
  k_transpose_w<<<dim3(64,16),blk,0,stream>>>(wu, wuT, 1024, 4096);
  k_transpose_w<<<dim3(16,64),blk,0,stream>>>(wd, wdT, 4096, 1024);

  k_rmsnorm<<<dim3(NROWS),blk,0,stream>>>(x, g1, xn);

  k_gemm<0><<<dim3(8,64),blk,0,stream>>>(xn, wqT, qb, nullptr, nullptr, nullptr, NROWS, 1024, 1024);
  k_gemm<0><<<dim3(8,64),blk,0,stream>>>(xn, wkT, kb, nullptr, nullptr, nullptr, NROWS, 1024, 1024);
  k_gemm<0><<<dim3(8,64),blk,0,stream>>>(xn, wvT, vb, nullptr, nullptr, nullptr, NROWS, 1024, 1024);

  k_rope<<<dim3((BATCH*SEQ*NH*32)/256),blk,0,stream>>>(qb, kb, rc, rs);
  k_transpose_v<<<dim3(32,64),blk,0,stream>>>(vb, vtb);
  k_attn<<<dim3(32,64),blk,0,stream>>>(qb, kb, vtb, xn);

  k_gemm<1><<<dim3(8,64),blk,0,stream>>>(xn, woT, nullptr, x1, x, nullptr, NROWS, 1024, 1024);

  k_rmsnorm<<<dim3(NROWS),blk,0,stream>>>(x1, g2, vb);

  k_gemm<0><<<dim3(32,64),blk,0,stream>>>(vb, wgT, gb, nullptr, nullptr, nullptr, NROWS, 4096, 1024);
  k_gemm<2><<<dim3(32,64),blk,0,stream>>>(vb, wuT, gb, nullptr, nullptr, gb, NROWS, 4096, 1024);
  k_gemm<1><<<dim3(8,64),blk,0,stream>>>(gb, wdT, nullptr, out, x1, nullptr, NROWS, 1024, 4096);
}

// Round 2
// 762.001 us; speedup vs baseline: 1.2434x; 1.2434x over previous
//
#include <hip/hip_runtime.h>
#include <cstdint>
#include <cstddef>

#define D_MODEL 1024
#define NH 16
#define HD 64
#define DFF 4096
#define BATCH 4
#define SEQ 2048
#define NROWS (BATCH*SEQ)

typedef uint16_t u16;
typedef __attribute__((ext_vector_type(8))) __bf16 bf16x8;
typedef __attribute__((ext_vector_type(4))) float f32x4;
typedef __attribute__((ext_vector_type(8))) u16 u16x8;
typedef __attribute__((ext_vector_type(4))) u16 u16x4;

__device__ __forceinline__ u16 f2bf(float x){
  union { float f; uint32_t u; } v; v.f = x;
  uint32_t r = v.u + 0x7fffu + ((v.u >> 16) & 1u);
  return (u16)(r >> 16);
}
__device__ __forceinline__ float bf2f(u16 h){
  union { uint32_t u; float f; } v; v.u = ((uint32_t)h) << 16; return v.f;
}
__device__ __forceinline__ void gload16(const void* g, void* l){
  __builtin_amdgcn_global_load_lds(
      (const __attribute__((address_space(1))) void*)g,
      (__attribute__((address_space(3))) void*)l, 16, 0, 0);
}
// swizzled read of a 16B chunk from a [rows][128B] LDS tile: byte ^= (row&7)<<4
__device__ __forceinline__ const bf16x8* swzp(const u16* base, int row, int chunk){
  return (const bf16x8*)((const char*)base + row*128 + (((chunk ^ (row & 7)) << 4)));
}

// ---------------- weight transpose: W[K][N] f32 -> WT[N][K] bf16 ----------------
__global__ __launch_bounds__(256) void k_transpose_w(const float* __restrict__ W,
                                                     u16* __restrict__ WT, int K, int N){
  __shared__ float tile[64][68];
  const int n0 = blockIdx.x*64, k0 = blockIdx.y*64;
  const int t = threadIdx.x;
  const int rr = t >> 4, cc = t & 15;
  #pragma unroll
  for (int i = 0; i < 4; ++i){
    int row = i*16 + rr;
    float4 v = *(const float4*)(W + (size_t)(k0+row)*N + n0 + cc*4);
    tile[row][cc*4+0] = v.x; tile[row][cc*4+1] = v.y;
    tile[row][cc*4+2] = v.z; tile[row][cc*4+3] = v.w;
  }
  __syncthreads();
  #pragma unroll
  for (int i = 0; i < 4; ++i){
    int nrow = i*16 + rr;
    int kc = cc*4;
    u16x4 o;
    o[0] = f2bf(tile[kc+0][nrow]);
    o[1] = f2bf(tile[kc+1][nrow]);
    o[2] = f2bf(tile[kc+2][nrow]);
    o[3] = f2bf(tile[kc+3][nrow]);
    *(u16x4*)(WT + (size_t)(n0+nrow)*K + k0 + kc) = o;
  }
}

// ---------------- RMSNorm: f32 in -> bf16 out ----------------
__global__ __launch_bounds__(256) void k_rmsnorm(const float* __restrict__ x,
                                                 const float* __restrict__ g,
                                                 u16* __restrict__ out){
  const int row = blockIdx.x; const int t = threadIdx.x;
  const float* xr = x + (size_t)row*D_MODEL;
  float4 v = *(const float4*)(xr + t*4);
  float ss = v.x*v.x + v.y*v.y + v.z*v.z + v.w*v.w;
  #pragma unroll
  for (int off = 1; off < 64; off <<= 1) ss += __shfl_xor(ss, off);
  __shared__ float wsum[4];
  if ((t & 63) == 0) wsum[t>>6] = ss;
  __syncthreads();
  float tot = wsum[0]+wsum[1]+wsum[2]+wsum[3];
  float sc = rsqrtf(tot * (1.0f/(float)D_MODEL) + 1e-6f);
  float4 gg = *(const float4*)(g + t*4);
  u16x4 o;
  o[0]=f2bf(v.x*sc*gg.x); o[1]=f2bf(v.y*sc*gg.y);
  o[2]=f2bf(v.z*sc*gg.z); o[3]=f2bf(v.w*sc*gg.w);
  *(u16x4*)(out + (size_t)row*D_MODEL + t*4) = o;
}

// ---------------- GEMM: C[M][N] = A[M][K](bf16) @ BT[N][K](bf16)^T ----------------
template<int MODE>
__global__ __launch_bounds__(256) void k_gemm(
    const u16* __restrict__ A, const u16* __restrict__ BT,
    u16* __restrict__ Cb, float* __restrict__ Cf,
    const float* __restrict__ resid, const u16* __restrict__ gate,
    int M, int N, int K)
{
  __shared__ __align__(16) u16 lA[128*64];
  __shared__ __align__(16) u16 lB[128*64];
  const int t = threadIdx.x;
  const int w = t >> 6, lane = t & 63, lr = lane & 15, lg = lane >> 4;
  const int wr = w >> 1, wc = w & 1;
  const int m0 = blockIdx.y * 128, n0 = blockIdx.x * 128;

  f32x4 acc[4][4];
  #pragma unroll
  for (int i=0;i<4;++i)
    #pragma unroll
    for (int j=0;j<4;++j) acc[i][j] = (f32x4){0.f,0.f,0.f,0.f};

  const int nkt = K >> 6;
  for (int kt = 0; kt < nkt; ++kt){
    __syncthreads();
    #pragma unroll
    for (int i = 0; i < 4; ++i){
      int c = i*256 + t;
      int r = c >> 3, ch = c & 7;
      gload16(A  + (size_t)(m0 + r)*K + kt*64 + ch*8, (char*)lA + i*4096 + w*1024);
      gload16(BT + (size_t)(n0 + r)*K + kt*64 + ch*8, (char*)lB + i*4096 + w*1024);
    }
    __syncthreads();
    #pragma unroll
    for (int ks = 0; ks < 2; ++ks){
      bf16x8 af[4], bfr[4];
      #pragma unroll
      for (int mi=0; mi<4; ++mi)
        af[mi] = *(const bf16x8*)(lA + (wr*64 + mi*16 + lr)*64 + ks*32 + lg*8);
      #pragma unroll
      for (int ni=0; ni<4; ++ni)
        bfr[ni] = *(const bf16x8*)(lB + (wc*64 + ni*16 + lr)*64 + ks*32 + lg*8);
      #pragma unroll
      for (int mi=0; mi<4; ++mi)
        #pragma unroll
        for (int ni=0; ni<4; ++ni)
          acc[mi][ni] = __builtin_amdgcn_mfma_f32_16x16x32_bf16(af[mi], bfr[ni], acc[mi][ni], 0,0,0);
    }
  }
  #pragma unroll
  for (int mi=0; mi<4; ++mi){
    #pragma unroll
    for (int ni=0; ni<4; ++ni){
      int mbase = m0 + wr*64 + mi*16 + lg*4;
      int n = n0 + wc*64 + ni*16 + lr;
      #pragma unroll
      for (int r=0;r<4;++r){
        size_t idx = (size_t)(mbase + r)*N + n;
        float vv = acc[mi][ni][r];
        if (MODE == 0) Cb[idx] = f2bf(vv);
        else if (MODE == 1) Cf[idx] = resid[idx] + vv;
        else { float gt = bf2f(gate[idx]); float sg = gt / (1.f + __expf(-gt)); Cb[idx] = f2bf(sg * vv); }
      }
    }
  }
}

// ---------------- RoPE in-place on q,k (bf16) ----------------
__global__ __launch_bounds__(256) void k_rope(u16* __restrict__ q, u16* __restrict__ k,
                                              const float* __restrict__ cs,
                                              const float* __restrict__ sn){
  int tid = blockIdx.x*256 + threadIdx.x;
  int d = tid & 31, h = (tid >> 5) & 15, s = (tid >> 9) & 2047, b = tid >> 20;
  size_t base = ((size_t)(b*SEQ + s))*D_MODEL + h*HD;
  float c1 = cs[s*HD + d],      s1 = sn[s*HD + d];
  float c2 = cs[s*HD + d + 32], s2 = sn[s*HD + d + 32];
  float q1 = bf2f(q[base+d]), q2 = bf2f(q[base+d+32]);
  q[base+d]    = f2bf(q1*c1 - q2*s1);
  q[base+d+32] = f2bf(q2*c2 + q1*s2);
  float k1 = bf2f(k[base+d]), k2 = bf2f(k[base+d+32]);
  k[base+d]    = f2bf(k1*c1 - k2*s1);
  k[base+d+32] = f2bf(k2*c2 + k1*s2);
}

// ---------------- V transpose: v[B*S][D] slice -> vt[(b*16+h)*64+d][S] ----------------
__global__ __launch_bounds__(256) void k_transpose_v(const u16* __restrict__ v,
                                                     u16* __restrict__ vt){
  const int s0 = blockIdx.x*64; const int bh = blockIdx.y;
  const int b = bh >> 4, h = bh & 15;
  __shared__ u16 tile[64][72];
  const int t = threadIdx.x;
  #pragma unroll
  for (int i=0;i<2;++i){
    int c = i*256 + t;
    int sr = c >> 3, ch = c & 7;
    u16x8 vv = *(const u16x8*)(v + (size_t)(b*SEQ + s0 + sr)*D_MODEL + h*HD + ch*8);
    #pragma unroll
    for (int j=0;j<8;++j) tile[sr][ch*8+j] = vv[j];
  }
  __syncthreads();
  #pragma unroll
  for (int i=0;i<2;++i){
    int c = i*256 + t;
    int dr = c >> 3, ch = c & 7;
    u16x8 o;
    #pragma unroll
    for (int j=0;j<8;++j) o[j] = tile[ch*8+j][dr];
    *(u16x8*)(vt + (size_t)(bh*HD + dr)*SEQ + s0 + ch*8) = o;
  }
}

// ---------------- causal flash attention ----------------
// grid: (B*NH, S/64); heavy q-tiles first. block 256 (4 waves x 16 q-rows).
// KVBLK=64; K/V/P LDS tiles XOR-swizzled (byte ^= (row&7)<<4) via pre-swizzled
// global source (rule #21: global_load_lds dest stays linear).
__global__ __launch_bounds__(256) void k_attn(const u16* __restrict__ q,
                                              const u16* __restrict__ k,
                                              const u16* __restrict__ vt,
                                              u16* __restrict__ ctx){
  const int bh = blockIdx.x;
  const int qt = (int)gridDim.y - 1 - (int)blockIdx.y;   // heavy blocks dispatch first
  const int b = bh >> 4, h = bh & 15;
  const int t = threadIdx.x, w = t >> 6, lane = t & 63, lr = lane & 15, lg = lane >> 4;
  __shared__ __align__(16) u16 kld[64*64];     // [kv][d]   swizzled
  __shared__ __align__(16) u16 vld[64*64];     // [d][kv]   swizzled
  __shared__ __align__(16) u16 pld[4][16*64];  // per-wave [qr][kv] swizzled

  const int qrow = qt*64 + w*16 + lr;
  const u16* qbase = q + (size_t)(b*SEQ + qrow)*D_MODEL + h*HD;
  bf16x8 qa0 = *(const bf16x8*)(qbase + lg*8);
  bf16x8 qa1 = *(const bf16x8*)(qbase + 32 + lg*8);

  float mreg[4], lreg[4]; f32x4 o[4];
  #pragma unroll
  for (int r=0;r<4;++r){ mreg[r] = -INFINITY; lreg[r] = 0.f; }
  #pragma unroll
  for (int g=0;g<4;++g) o[g] = (f32x4){0.f,0.f,0.f,0.f};

  for (int it = 0; it <= qt; ++it){
    const int kv0 = it*64;
    __syncthreads();
    #pragma unroll
    for (int i=0;i<2;++i){
      int ci = i*256 + t;
      int row = ci >> 3, c = ci & 7, cg = c ^ (row & 7);
      gload16(k  + (size_t)(b*SEQ + kv0 + row)*D_MODEL + h*HD + cg*8,
              (char*)kld + i*4096 + w*1024);
      gload16(vt + (size_t)(bh*HD + row)*SEQ + kv0 + cg*8,
              (char*)vld + i*4096 + w*1024);
    }
    __syncthreads();

    // ---- QK^T: S[16 qr][64 kv] per wave ----
    f32x4 s[4];
    #pragma unroll
    for (int nf=0;nf<4;++nf) s[nf] = (f32x4){0.f,0.f,0.f,0.f};
    #pragma unroll
    for (int nf=0;nf<4;++nf){
      int row = nf*16 + lr;
      s[nf] = __builtin_amdgcn_mfma_f32_16x16x32_bf16(qa0, *swzp(kld,row,  lg), s[nf], 0,0,0);
      s[nf] = __builtin_amdgcn_mfma_f32_16x16x32_bf16(qa1, *swzp(kld,row,4+lg), s[nf], 0,0,0);
    }
    // ---- mask + online softmax ----
    const bool domask = (it == qt);
    float p[4][4], rm[4];
    #pragma unroll
    for (int r=0;r<4;++r) rm[r] = -INFINITY;
    #pragma unroll
    for (int nf=0;nf<4;++nf)
      #pragma unroll
      for (int r=0;r<4;++r){
        float v = s[nf][r]*0.125f;
        if (domask && (kv0 + nf*16 + lr > qt*64 + w*16 + lg*4 + r)) v = -INFINITY;
        p[nf][r] = v; rm[r] = fmaxf(rm[r], v);
      }
    #pragma unroll
    for (int off=1; off<16; off<<=1)
      #pragma unroll
      for (int r=0;r<4;++r) rm[r] = fmaxf(rm[r], __shfl_xor(rm[r], off));
    float al[4];
    #pragma unroll
    for (int r=0;r<4;++r){
      float mn = fmaxf(mreg[r], rm[r]);
      al[r] = __expf(mreg[r] - mn);
      mreg[r] = mn;
    }
    #pragma unroll
    for (int nf=0;nf<4;++nf)
      #pragma unroll
      for (int r=0;r<4;++r) p[nf][r] = __expf(p[nf][r] - mreg[r]);
    float ps[4];
    #pragma unroll
    for (int r=0;r<4;++r) ps[r] = p[0][r]+p[1][r]+p[2][r]+p[3][r];
    #pragma unroll
    for (int off=1; off<16; off<<=1)
      #pragma unroll
      for (int r=0;r<4;++r) ps[r] += __shfl_xor(ps[r], off);
    #pragma unroll
    for (int r=0;r<4;++r) lreg[r] = lreg[r]*al[r] + ps[r];
    #pragma unroll
    for (int g=0;g<4;++g)
      #pragma unroll
      for (int r=0;r<4;++r) o[g][r] *= al[r];

    // ---- P -> LDS (swizzled), re-layout for PV A-frag ----
    #pragma unroll
    for (int nf=0;nf<4;++nf)
      #pragma unroll
      for (int r=0;r<4;++r){
        int prow = lg*4 + r;
        int pb = ((nf*16 + lr)*2) ^ ((prow & 7) << 4);
        *(u16*)((char*)(pld[w]) + prow*128 + pb) = f2bf(p[nf][r]);
      }
    bf16x8 pa0 = *swzp(pld[w], lr,   lg);
    bf16x8 pa1 = *swzp(pld[w], lr, 4+lg);
    #pragma unroll
    for (int g=0;g<4;++g){
      o[g] = __builtin_amdgcn_mfma_f32_16x16x32_bf16(pa0, *swzp(vld, g*16+lr,   lg), o[g], 0,0,0);
      o[g] = __builtin_amdgcn_mfma_f32_16x16x32_bf16(pa1, *swzp(vld, g*16+lr, 4+lg), o[g], 0,0,0);
    }
  }
  #pragma unroll
  for (int g=0; g<4; ++g){
    int col = h*HD + g*16 + lr;
    #pragma unroll
    for (int r=0;r<4;++r){
      int row = qt*64 + w*16 + lg*4 + r;
      ctx[(size_t)(b*SEQ + row)*D_MODEL + col] = f2bf(o[g][r] / lreg[r]);
    }
  }
}

extern "C" void kernel_launch(void* const* d_in, const int* in_sizes, int n_in,
                              void* d_out, int out_size, void* d_ws, size_t ws_size,
                              hipStream_t stream){
  const float* x  = (const float*)d_in[0];
  const float* rc = (const float*)d_in[1];
  const float* rs = (const float*)d_in[2];
  const float* g1 = (const float*)d_in[3];
  const float* g2 = (const float*)d_in[4];
  const float* wq = (const float*)d_in[5];
  const float* wk = (const float*)d_in[6];
  const float* wv = (const float*)d_in[7];
  const float* wo = (const float*)d_in[8];
  const float* wg = (const float*)d_in[9];
  const float* wu = (const float*)d_in[10];
  const float* wd = (const float*)d_in[11];
  float* out = (float*)d_out;

  char* ws = (char*)d_ws;
  const size_t MB = 1024*1024;
  u16* wqT = (u16*)(ws + 0);
  u16* wkT = (u16*)(ws + 2*MB);
  u16* wvT = (u16*)(ws + 4*MB);
  u16* woT = (u16*)(ws + 6*MB);
  u16* wgT = (u16*)(ws + 8*MB);
  u16* wuT = (u16*)(ws + 16*MB);
  u16* wdT = (u16*)(ws + 24*MB);
  float* x1 = (float*)(ws + 32*MB);
  u16* xn  = (u16*)(ws + 64*MB);    // reused as ctx after QKV GEMMs
  u16* qb  = (u16*)(ws + 80*MB);
  u16* kb  = (u16*)(ws + 96*MB);
  u16* vb  = (u16*)(ws + 112*MB);   // reused as xn2 after V-transpose
  u16* vtb = (u16*)(ws + 128*MB);
  u16* gb  = (u16*)(ws + 144*MB);   // 64MB; gate then h in-place

  dim3 blk(256);
  k_transpose_w<<<dim3(16,16),blk,0,stream>>>(wq, wqT, 1024, 1024);
  k_transpose_w<<<dim3(16,16),blk,0,stream>>>(wk, wkT, 1024, 1024);
  k_transpose_w<<<dim3(16,16),blk,0,stream>>>(wv, wvT, 1024, 1024);
  k_transpose_w<<<dim3(16,16),blk,0,stream>>>(wo, woT, 1024, 1024);
  k_transpose_w<<<dim3(64,16),blk,0,stream>>>(wg, wgT, 1024, 4096);
  k_transpose_w<<<dim3(64,16),blk,0,stream>>>(wu, wuT, 1024, 4096);
  k_transpose_w<<<dim3(16,64),blk,0,stream>>>(wd, wdT, 4096, 1024);

  k_rmsnorm<<<dim3(NROWS),blk,0,stream>>>(x, g1, xn);

  k_gemm<0><<<dim3(8,64),blk,0,stream>>>(xn, wqT, qb, nullptr, nullptr, nullptr, NROWS, 1024, 1024);
  k_gemm<0><<<dim3(8,64),blk,0,stream>>>(xn, wkT, kb, nullptr, nullptr, nullptr, NROWS, 1024, 1024);
  k_gemm<0><<<dim3(8,64),blk,0,stream>>>(xn, wvT, vb, nullptr, nullptr, nullptr, NROWS, 1024, 1024);

  k_rope<<<dim3((BATCH*SEQ*NH*32)/256),blk,0,stream>>>(qb, kb, rc, rs);
  k_transpose_v<<<dim3(32,64),blk,0,stream>>>(vb, vtb);
  k_attn<<<dim3(64,32),blk,0,stream>>>(qb, kb, vtb, xn);

  k_gemm<1><<<dim3(8,64),blk,0,stream>>>(xn, woT, nullptr, x1, x, nullptr, NROWS, 1024, 1024);

  k_rmsnorm<<<dim3(NROWS),blk,0,stream>>>(x1, g2, vb);

  k_gemm<0><<<dim3(32,64),blk,0,stream>>>(vb, wgT, gb, nullptr, nullptr, nullptr, NROWS, 4096, 1024);
  k_gemm<2><<<dim3(32,64),blk,0,stream>>>(vb, wuT, gb, nullptr, nullptr, gb, NROWS, 4096, 1024);
  k_gemm<1><<<dim3(8,64),blk,0,stream>>>(gb, wdT, nullptr, out, x1, nullptr, NROWS, 1024, 4096);
}

// Round 3
// 643.809 us; speedup vs baseline: 1.4717x; 1.1836x over previous
//
#include <hip/hip_runtime.h>
#include <cstdint>
#include <cstddef>

#define D_MODEL 1024
#define NH 16
#define HD 64
#define DFF 4096
#define BATCH 4
#define SEQ 2048
#define NROWS (BATCH*SEQ)
#define QKVW 3072

typedef uint16_t u16;
typedef __attribute__((ext_vector_type(8))) __bf16 bf16x8;
typedef __attribute__((ext_vector_type(4))) float f32x4;
typedef __attribute__((ext_vector_type(8))) u16 u16x8;
typedef __attribute__((ext_vector_type(4))) u16 u16x4;

__device__ __forceinline__ u16 f2bf(float x){
  union { float f; uint32_t u; } v; v.f = x;
  uint32_t r = v.u + 0x7fffu + ((v.u >> 16) & 1u);
  return (u16)(r >> 16);
}
__device__ __forceinline__ float bf2f(u16 h){
  union { uint32_t u; float f; } v; v.u = ((uint32_t)h) << 16; return v.f;
}
__device__ __forceinline__ void gload16(const void* g, void* l){
  __builtin_amdgcn_global_load_lds(
      (const __attribute__((address_space(1))) void*)g,
      (__attribute__((address_space(3))) void*)l, 16, 0, 0);
}
// swizzled read of a 16B chunk from a [rows][128B] LDS tile: byte ^= (row&7)<<4
__device__ __forceinline__ const bf16x8* swzp(const u16* base, int row, int chunk){
  return (const bf16x8*)((const char*)base + row*128 + (((chunk ^ (row & 7)) << 4)));
}

// ---------------- weight transpose: W[K][N] f32 -> WT[N][K] bf16 ----------------
__global__ __launch_bounds__(256) void k_transpose_w(const float* __restrict__ W,
                                                     u16* __restrict__ WT, int K, int N){
  __shared__ float tile[64][68];
  const int n0 = blockIdx.x*64, k0 = blockIdx.y*64;
  const int t = threadIdx.x;
  const int rr = t >> 4, cc = t & 15;
  #pragma unroll
  for (int i = 0; i < 4; ++i){
    int row = i*16 + rr;
    float4 v = *(const float4*)(W + (size_t)(k0+row)*N + n0 + cc*4);
    tile[row][cc*4+0] = v.x; tile[row][cc*4+1] = v.y;
    tile[row][cc*4+2] = v.z; tile[row][cc*4+3] = v.w;
  }
  __syncthreads();
  #pragma unroll
  for (int i = 0; i < 4; ++i){
    int nrow = i*16 + rr;
    int kc = cc*4;
    u16x4 o;
    o[0] = f2bf(tile[kc+0][nrow]);
    o[1] = f2bf(tile[kc+1][nrow]);
    o[2] = f2bf(tile[kc+2][nrow]);
    o[3] = f2bf(tile[kc+3][nrow]);
    *(u16x4*)(WT + (size_t)(n0+nrow)*K + k0 + kc) = o;
  }
}

// ---------------- RMSNorm: f32 in -> bf16 out ----------------
__global__ __launch_bounds__(256) void k_rmsnorm(const float* __restrict__ x,
                                                 const float* __restrict__ g,
                                                 u16* __restrict__ out){
  const int row = blockIdx.x; const int t = threadIdx.x;
  const float* xr = x + (size_t)row*D_MODEL;
  float4 v = *(const float4*)(xr + t*4);
  float ss = v.x*v.x + v.y*v.y + v.z*v.z + v.w*v.w;
  #pragma unroll
  for (int off = 1; off < 64; off <<= 1) ss += __shfl_xor(ss, off);
  __shared__ float wsum[4];
  if ((t & 63) == 0) wsum[t>>6] = ss;
  __syncthreads();
  float tot = wsum[0]+wsum[1]+wsum[2]+wsum[3];
  float sc = rsqrtf(tot * (1.0f/(float)D_MODEL) + 1e-6f);
  float4 gg = *(const float4*)(g + t*4);
  u16x4 o;
  o[0]=f2bf(v.x*sc*gg.x); o[1]=f2bf(v.y*sc*gg.y);
  o[2]=f2bf(v.z*sc*gg.z); o[3]=f2bf(v.w*sc*gg.w);
  *(u16x4*)(out + (size_t)row*D_MODEL + t*4) = o;
}

// ---------------- 256-tile GEMM, counted-vmcnt pipelined ----------------
// C[M][N] = A[M][K](bf16) @ BT[N][K](bf16)^T.  512 thr = 8 waves (2M x 4N).
// BM=256, BK=64, BN=NREP*64.  Per wave: 128 x NREP*16 output (8 x NREP frags).
// Schedule per K-tile (buf p = kt&1):
//   P1: ds_read af[0..3]+bfr[lo]; MFMA Q1    P2: ds_read rest; MFMA Q2;
//       lgkmcnt(0); barrier  (all reads of buf p retired -> overwrite legal)
//   P3: stage A(kt+2)->buf p; MFMA Q3        P4: stage B(kt+2); MFMA Q4;
//       vmcnt(L) (tile kt+1 landed, kt+2's L loads stay in flight); barrier
// MODE 0: Cb=bf16(acc); 1: Cf=resid+acc; 2: Cb=bf16(silu(gate)*acc)
template<int NREP, int MODE>
__global__ __launch_bounds__(512, 2) void k_gemm8(
    const u16* __restrict__ A, const u16* __restrict__ BT,
    u16* __restrict__ Cb, float* __restrict__ Cf,
    const float* __restrict__ resid, const u16* __restrict__ gate,
    int M, int N, int K, int nbx)
{
  __shared__ __align__(16) u16 lA[2][16384];
  __shared__ __align__(16) u16 lB[2][NREP*4096];
  const int t = threadIdx.x, wid = t >> 6, lane = t & 63, lr = lane & 15, lg = lane >> 4;
  const int wr = wid >> 2, wc = wid & 3;
  const int nwg = gridDim.x, bid = blockIdx.x;
  const int wg = (bid & 7) * (nwg >> 3) + (bid >> 3);   // bijective: nwg % 8 == 0
  const int bx = wg % nbx, by = wg / nbx;
  const int m0 = by * 256, n0 = bx * (NREP * 64);
  const int NT = K >> 6;

  f32x4 acc[8][NREP];
  #pragma unroll
  for (int i=0;i<8;++i)
    #pragma unroll
    for (int j=0;j<NREP;++j) acc[i][j] = (f32x4){0.f,0.f,0.f,0.f};

  #define STAGE_A(kt,p) { \
    _Pragma("unroll") \
    for (int i=0;i<4;++i){ \
      int ci = i*512 + t; int row = ci>>3, c = ci&7; \
      gload16(A + (size_t)(m0+row)*K + (kt)*64 + ((c ^ (row&7))*8), \
              (char*)lA[p] + i*8192 + wid*1024); } }
  #define STAGE_B(kt,p) { \
    _Pragma("unroll") \
    for (int i=0;i<NREP;++i){ \
      int ci = i*512 + t; int row = ci>>3, c = ci&7; \
      gload16(BT + (size_t)(n0+row)*K + (kt)*64 + ((c ^ (row&7))*8), \
              (char*)lB[p] + i*8192 + wid*1024); } }
  #define WAIT_L() { if constexpr (NREP==4) asm volatile("s_waitcnt vmcnt(8)" ::: "memory"); \
                     else                   asm volatile("s_waitcnt vmcnt(6)" ::: "memory"); }

  STAGE_A(0,0); STAGE_B(0,0);
  STAGE_A(1,1); STAGE_B(1,1);
  WAIT_L();
  __builtin_amdgcn_sched_barrier(0);
  __builtin_amdgcn_s_barrier();
  __builtin_amdgcn_sched_barrier(0);

  for (int kt = 0; kt < NT; ++kt){
    const int p = kt & 1;
    const u16* a = lA[p];
    const u16* b = lB[p];
    bf16x8 af[8][2], bfr[NREP][2];
    // ---- P1 ----
    #pragma unroll
    for (int mi=0;mi<4;++mi){
      int row = wr*128 + mi*16 + lr;
      af[mi][0] = *swzp(a, row,   lg);
      af[mi][1] = *swzp(a, row, 4+lg);
    }
    #pragma unroll
    for (int ni=0;ni<NREP/2;++ni){
      int row = wc*(NREP*16) + ni*16 + lr;
      bfr[ni][0] = *swzp(b, row,   lg);
      bfr[ni][1] = *swzp(b, row, 4+lg);
    }
    __builtin_amdgcn_s_setprio(1);
    #pragma unroll
    for (int mi=0;mi<4;++mi)
      #pragma unroll
      for (int ni=0;ni<NREP/2;++ni){
        acc[mi][ni] = __builtin_amdgcn_mfma_f32_16x16x32_bf16(af[mi][0], bfr[ni][0], acc[mi][ni], 0,0,0);
        acc[mi][ni] = __builtin_amdgcn_mfma_f32_16x16x32_bf16(af[mi][1], bfr[ni][1], acc[mi][ni], 0,0,0);
      }
    __builtin_amdgcn_s_setprio(0);
    // ---- P2 ----
    #pragma unroll
    for (int mi=4;mi<8;++mi){
      int row = wr*128 + mi*16 + lr;
      af[mi][0] = *swzp(a, row,   lg);
      af[mi][1] = *swzp(a, row, 4+lg);
    }
    #pragma unroll
    for (int ni=NREP/2;ni<NREP;++ni){
      int row = wc*(NREP*16) + ni*16 + lr;
      bfr[ni][0] = *swzp(b, row,   lg);
      bfr[ni][1] = *swzp(b, row, 4+lg);
    }
    __builtin_amdgcn_s_setprio(1);
    #pragma unroll
    for (int mi=4;mi<8;++mi)
      #pragma unroll
      for (int ni=0;ni<NREP/2;++ni){
        acc[mi][ni] = __builtin_amdgcn_mfma_f32_16x16x32_bf16(af[mi][0], bfr[ni][0], acc[mi][ni], 0,0,0);
        acc[mi][ni] = __builtin_amdgcn_mfma_f32_16x16x32_bf16(af[mi][1], bfr[ni][1], acc[mi][ni], 0,0,0);
      }
    __builtin_amdgcn_s_setprio(0);
    asm volatile("s_waitcnt lgkmcnt(0)" ::: "memory");
    __builtin_amdgcn_sched_barrier(0);
    __builtin_amdgcn_s_barrier();
    __builtin_amdgcn_sched_barrier(0);
    // ---- P3 ----
    if (kt + 2 < NT) STAGE_A(kt+2, p);
    __builtin_amdgcn_s_setprio(1);
    #pragma unroll
    for (int mi=0;mi<4;++mi)
      #pragma unroll
      for (int ni=NREP/2;ni<NREP;++ni){
        acc[mi][ni] = __builtin_amdgcn_mfma_f32_16x16x32_bf16(af[mi][0], bfr[ni][0], acc[mi][ni], 0,0,0);
        acc[mi][ni] = __builtin_amdgcn_mfma_f32_16x16x32_bf16(af[mi][1], bfr[ni][1], acc[mi][ni], 0,0,0);
      }
    __builtin_amdgcn_s_setprio(0);
    // ---- P4 ----
    if (kt + 2 < NT) STAGE_B(kt+2, p);
    __builtin_amdgcn_s_setprio(1);
    #pragma unroll
    for (int mi=4;mi<8;++mi)
      #pragma unroll
      for (int ni=NREP/2;ni<NREP;++ni){
        acc[mi][ni] = __builtin_amdgcn_mfma_f32_16x16x32_bf16(af[mi][0], bfr[ni][0], acc[mi][ni], 0,0,0);
        acc[mi][ni] = __builtin_amdgcn_mfma_f32_16x16x32_bf16(af[mi][1], bfr[ni][1], acc[mi][ni], 0,0,0);
      }
    __builtin_amdgcn_s_setprio(0);
    __builtin_amdgcn_sched_barrier(0);
    if (kt + 2 < NT) { WAIT_L(); }
    else             { asm volatile("s_waitcnt vmcnt(0)" ::: "memory"); }
    __builtin_amdgcn_s_barrier();
    __builtin_amdgcn_sched_barrier(0);
  }

  #pragma unroll
  for (int mi=0;mi<8;++mi)
    #pragma unroll
    for (int ni=0;ni<NREP;++ni){
      int mbase = m0 + wr*128 + mi*16 + lg*4;
      int n = n0 + wc*(NREP*16) + ni*16 + lr;
      #pragma unroll
      for (int r=0;r<4;++r){
        size_t idx = (size_t)(mbase + r)*N + n;
        float vv = acc[mi][ni][r];
        if (MODE == 0) Cb[idx] = f2bf(vv);
        else if (MODE == 1) Cf[idx] = resid[idx] + vv;
        else { float gt = bf2f(gate[idx]); float sg = gt / (1.f + __expf(-gt)); Cb[idx] = f2bf(sg * vv); }
      }
    }
  #undef STAGE_A
  #undef STAGE_B
  #undef WAIT_L
}

// ---------------- RoPE in-place on fused qkv (bf16), row stride 3072 ----------------
__global__ __launch_bounds__(256) void k_rope(u16* __restrict__ qkv,
                                              const float* __restrict__ cs,
                                              const float* __restrict__ sn){
  int tid = blockIdx.x*256 + threadIdx.x;
  int d = tid & 31, h = (tid >> 5) & 15, s = (tid >> 9) & 2047, b = tid >> 20;
  size_t base = ((size_t)(b*SEQ + s))*QKVW + h*HD;
  float c1 = cs[s*HD + d],      s1 = sn[s*HD + d];
  float c2 = cs[s*HD + d + 32], s2 = sn[s*HD + d + 32];
  float q1 = bf2f(qkv[base+d]), q2 = bf2f(qkv[base+d+32]);
  qkv[base+d]    = f2bf(q1*c1 - q2*s1);
  qkv[base+d+32] = f2bf(q2*c2 + q1*s2);
  size_t kb = base + 1024;
  float k1 = bf2f(qkv[kb+d]), k2 = bf2f(qkv[kb+d+32]);
  qkv[kb+d]    = f2bf(k1*c1 - k2*s1);
  qkv[kb+d+32] = f2bf(k2*c2 + k1*s2);
}

// ---------------- V transpose: qkv v-slice -> vt[(b*16+h)*64+d][S] ----------------
__global__ __launch_bounds__(256) void k_transpose_v(const u16* __restrict__ qkv,
                                                     u16* __restrict__ vt){
  const int s0 = blockIdx.x*64; const int bh = blockIdx.y;
  const int b = bh >> 4, h = bh & 15;
  __shared__ u16 tile[64][72];
  const int t = threadIdx.x;
  #pragma unroll
  for (int i=0;i<2;++i){
    int c = i*256 + t;
    int sr = c >> 3, ch = c & 7;
    u16x8 vv = *(const u16x8*)(qkv + (size_t)(b*SEQ + s0 + sr)*QKVW + 2048 + h*HD + ch*8);
    #pragma unroll
    for (int j=0;j<8;++j) tile[sr][ch*8+j] = vv[j];
  }
  __syncthreads();
  #pragma unroll
  for (int i=0;i<2;++i){
    int c = i*256 + t;
    int dr = c >> 3, ch = c & 7;
    u16x8 o;
    #pragma unroll
    for (int j=0;j<8;++j) o[j] = tile[ch*8+j][dr];
    *(u16x8*)(vt + (size_t)(bh*HD + dr)*SEQ + s0 + ch*8) = o;
  }
}

// ---------------- causal flash attention (q,k from fused qkv, stride 3072) ----------------
__global__ __launch_bounds__(256) void k_attn(const u16* __restrict__ qkv,
                                              const u16* __restrict__ vt,
                                              u16* __restrict__ ctx){
  const int bh = blockIdx.x;
  const int qt = (int)gridDim.y - 1 - (int)blockIdx.y;   // heavy blocks dispatch first
  const int b = bh >> 4, h = bh & 15;
  const int t = threadIdx.x, w = t >> 6, lane = t & 63, lr = lane & 15, lg = lane >> 4;
  __shared__ __align__(16) u16 kld[64*64];     // [kv][d]   swizzled
  __shared__ __align__(16) u16 vld[64*64];     // [d][kv]   swizzled
  __shared__ __align__(16) u16 pld[4][16*64];  // per-wave [qr][kv] swizzled

  const int qrow = qt*64 + w*16 + lr;
  const u16* qbase = qkv + (size_t)(b*SEQ + qrow)*QKVW + h*HD;
  bf16x8 qa0 = *(const bf16x8*)(qbase + lg*8);
  bf16x8 qa1 = *(const bf16x8*)(qbase + 32 + lg*8);

  float mreg[4], lreg[4]; f32x4 o[4];
  #pragma unroll
  for (int r=0;r<4;++r){ mreg[r] = -INFINITY; lreg[r] = 0.f; }
  #pragma unroll
  for (int g=0;g<4;++g) o[g] = (f32x4){0.f,0.f,0.f,0.f};

  for (int it = 0; it <= qt; ++it){
    const int kv0 = it*64;
    __syncthreads();
    #pragma unroll
    for (int i=0;i<2;++i){
      int ci = i*256 + t;
      int row = ci >> 3, c = ci & 7, cg = c ^ (row & 7);
      gload16(qkv + (size_t)(b*SEQ + kv0 + row)*QKVW + 1024 + h*HD + cg*8,
              (char*)kld + i*4096 + w*1024);
      gload16(vt + (size_t)(bh*HD + row)*SEQ + kv0 + cg*8,
              (char*)vld + i*4096 + w*1024);
    }
    __syncthreads();

    f32x4 s[4];
    #pragma unroll
    for (int nf=0;nf<4;++nf) s[nf] = (f32x4){0.f,0.f,0.f,0.f};
    #pragma unroll
    for (int nf=0;nf<4;++nf){
      int row = nf*16 + lr;
      s[nf] = __builtin_amdgcn_mfma_f32_16x16x32_bf16(qa0, *swzp(kld,row,  lg), s[nf], 0,0,0);
      s[nf] = __builtin_amdgcn_mfma_f32_16x16x32_bf16(qa1, *swzp(kld,row,4+lg), s[nf], 0,0,0);
    }
    const bool domask = (it == qt);
    float p[4][4], rm[4];
    #pragma unroll
    for (int r=0;r<4;++r) rm[r] = -INFINITY;
    #pragma unroll
    for (int nf=0;nf<4;++nf)
      #pragma unroll
      for (int r=0;r<4;++r){
        float v = s[nf][r]*0.125f;
        if (domask && (kv0 + nf*16 + lr > qt*64 + w*16 + lg*4 + r)) v = -INFINITY;
        p[nf][r] = v; rm[r] = fmaxf(rm[r], v);
      }
    #pragma unroll
    for (int off=1; off<16; off<<=1)
      #pragma unroll
      for (int r=0;r<4;++r) rm[r] = fmaxf(rm[r], __shfl_xor(rm[r], off));
    float al[4];
    #pragma unroll
    for (int r=0;r<4;++r){
      float mn = fmaxf(mreg[r], rm[r]);
      al[r] = __expf(mreg[r] - mn);
      mreg[r] = mn;
    }
    #pragma unroll
    for (int nf=0;nf<4;++nf)
      #pragma unroll
      for (int r=0;r<4;++r) p[nf][r] = __expf(p[nf][r] - mreg[r]);
    float ps[4];
    #pragma unroll
    for (int r=0;r<4;++r) ps[r] = p[0][r]+p[1][r]+p[2][r]+p[3][r];
    #pragma unroll
    for (int off=1; off<16; off<<=1)
      #pragma unroll
      for (int r=0;r<4;++r) ps[r] += __shfl_xor(ps[r], off);
    #pragma unroll
    for (int r=0;r<4;++r) lreg[r] = lreg[r]*al[r] + ps[r];
    #pragma unroll
    for (int g=0;g<4;++g)
      #pragma unroll
      for (int r=0;r<4;++r) o[g][r] *= al[r];

    #pragma unroll
    for (int nf=0;nf<4;++nf)
      #pragma unroll
      for (int r=0;r<4;++r){
        int prow = lg*4 + r;
        int pb = ((nf*16 + lr)*2) ^ ((prow & 7) << 4);
        *(u16*)((char*)(pld[w]) + prow*128 + pb) = f2bf(p[nf][r]);
      }
    bf16x8 pa0 = *swzp(pld[w], lr,   lg);
    bf16x8 pa1 = *swzp(pld[w], lr, 4+lg);
    #pragma unroll
    for (int g=0;g<4;++g){
      o[g] = __builtin_amdgcn_mfma_f32_16x16x32_bf16(pa0, *swzp(vld, g*16+lr,   lg), o[g], 0,0,0);
      o[g] = __builtin_amdgcn_mfma_f32_16x16x32_bf16(pa1, *swzp(vld, g*16+lr, 4+lg), o[g], 0,0,0);
    }
  }
  #pragma unroll
  for (int g=0; g<4; ++g){
    int col = h*HD + g*16 + lr;
    #pragma unroll
    for (int r=0;r<4;++r){
      int row = qt*64 + w*16 + lg*4 + r;
      ctx[(size_t)(b*SEQ + row)*D_MODEL + col] = f2bf(o[g][r] / lreg[r]);
    }
  }
}

extern "C" void kernel_launch(void* const* d_in, const int* in_sizes, int n_in,
                              void* d_out, int out_size, void* d_ws, size_t ws_size,
                              hipStream_t stream){
  const float* x  = (const float*)d_in[0];
  const float* rc = (const float*)d_in[1];
  const float* rs = (const float*)d_in[2];
  const float* g1 = (const float*)d_in[3];
  const float* g2 = (const float*)d_in[4];
  const float* wq = (const float*)d_in[5];
  const float* wk = (const float*)d_in[6];
  const float* wv = (const float*)d_in[7];
  const float* wo = (const float*)d_in[8];
  const float* wg = (const float*)d_in[9];
  const float* wu = (const float*)d_in[10];
  const float* wd = (const float*)d_in[11];
  float* out = (float*)d_out;

  char* ws = (char*)d_ws;
  const size_t MB = 1024*1024;
  u16* wqkvT = (u16*)(ws + 0);          // [3072][1024] bf16
  u16* woT   = (u16*)(ws + 6*MB);
  u16* wgT   = (u16*)(ws + 8*MB);
  u16* wuT   = (u16*)(ws + 16*MB);
  u16* wdT   = (u16*)(ws + 24*MB);
  float* x1  = (float*)(ws + 32*MB);
  u16* xn    = (u16*)(ws + 64*MB);      // xn -> ctx -> xn2 (sequential reuse)
  u16* qkv   = (u16*)(ws + 80*MB);      // [8192][3072]
  u16* vtb   = (u16*)(ws + 128*MB);
  u16* gb    = (u16*)(ws + 144*MB);     // [8192][4096] gate then h

  dim3 blk(256);
  k_transpose_w<<<dim3(16,16),blk,0,stream>>>(wq, wqkvT,             1024, 1024);
  k_transpose_w<<<dim3(16,16),blk,0,stream>>>(wk, wqkvT + 1024*1024, 1024, 1024);
  k_transpose_w<<<dim3(16,16),blk,0,stream>>>(wv, wqkvT + 2048*1024, 1024, 1024);
  k_transpose_w<<<dim3(16,16),blk,0,stream>>>(wo, woT, 1024, 1024);
  k_transpose_w<<<dim3(64,16),blk,0,stream>>>(wg, wgT, 1024, 4096);
  k_transpose_w<<<dim3(64,16),blk,0,stream>>>(wu, wuT, 1024, 4096);
  k_transpose_w<<<dim3(16,64),blk,0,stream>>>(wd, wdT, 4096, 1024);

  k_rmsnorm<<<dim3(NROWS),blk,0,stream>>>(x, g1, xn);

  k_gemm8<4,0><<<dim3(384),dim3(512),0,stream>>>(xn, wqkvT, qkv, nullptr, nullptr, nullptr,
                                                 NROWS, QKVW, 1024, 12);

  k_rope<<<dim3((BATCH*SEQ*NH*32)/256),blk,0,stream>>>(qkv, rc, rs);
  k_transpose_v<<<dim3(32,64),blk,0,stream>>>(qkv, vtb);
  k_attn<<<dim3(64,32),blk,0,stream>>>(qkv, vtb, xn);

  k_gemm8<2,1><<<dim3(256),dim3(512),0,stream>>>(xn, woT, nullptr, x1, x, nullptr,
                                                 NROWS, 1024, 1024, 8);

  k_rmsnorm<<<dim3(NROWS),blk,0,stream>>>(x1, g2, xn);

  k_gemm8<4,0><<<dim3(512),dim3(512),0,stream>>>(xn, wgT, gb, nullptr, nullptr, nullptr,
                                                 NROWS, 4096, 1024, 16);
  k_gemm8<4,2><<<dim3(512),dim3(512),0,stream>>>(xn, wuT, gb, nullptr, nullptr, gb,
                                                 NROWS, 4096, 1024, 16);
  k_gemm8<2,1><<<dim3(256),dim3(512),0,stream>>>(gb, wdT, nullptr, out, x1, nullptr,
                                                 NROWS, 1024, 4096, 8);
}

// Round 9
// 597.781 us; speedup vs baseline: 1.5850x; 1.0770x over previous
//
#include <hip/hip_runtime.h>
#include <cstdint>
#include <cstddef>

#define D_MODEL 1024
#define NH 16
#define HD 64
#define DFF 4096
#define BATCH 4
#define SEQ 2048
#define NROWS (BATCH*SEQ)
#define QKVW 3072

typedef uint16_t u16;
typedef __attribute__((ext_vector_type(8))) __bf16 bf16x8;
typedef __attribute__((ext_vector_type(4))) float f32x4;
typedef __attribute__((ext_vector_type(8))) u16 u16x8;
typedef __attribute__((ext_vector_type(4))) u16 u16x4;

__device__ __forceinline__ u16 f2bf(float x){
  union { float f; uint32_t u; } v; v.f = x;
  uint32_t r = v.u + 0x7fffu + ((v.u >> 16) & 1u);
  return (u16)(r >> 16);
}
__device__ __forceinline__ float bf2f(u16 h){
  union { uint32_t u; float f; } v; v.u = ((uint32_t)h) << 16; return v.f;
}
__device__ __forceinline__ void gload16(const void* g, void* l){
  __builtin_amdgcn_global_load_lds(
      (const __attribute__((address_space(1))) void*)g,
      (__attribute__((address_space(3))) void*)l, 16, 0, 0);
}
// swizzled read of a 16B chunk from a [rows][128B] LDS tile: byte ^= (row&7)<<4
__device__ __forceinline__ const bf16x8* swzp(const u16* base, int row, int chunk){
  return (const bf16x8*)((const char*)base + row*128 + (((chunk ^ (row & 7)) << 4)));
}

// ---------------- weight transpose: W[K][N] f32 -> WT[N][K] bf16 ----------------
__global__ __launch_bounds__(256) void k_transpose_w(const float* __restrict__ W,
                                                     u16* __restrict__ WT, int K, int N){
  __shared__ float tile[64][68];
  const int n0 = blockIdx.x*64, k0 = blockIdx.y*64;
  const int t = threadIdx.x;
  const int rr = t >> 4, cc = t & 15;
  #pragma unroll
  for (int i = 0; i < 4; ++i){
    int row = i*16 + rr;
    float4 v = *(const float4*)(W + (size_t)(k0+row)*N + n0 + cc*4);
    tile[row][cc*4+0] = v.x; tile[row][cc*4+1] = v.y;
    tile[row][cc*4+2] = v.z; tile[row][cc*4+3] = v.w;
  }
  __syncthreads();
  #pragma unroll
  for (int i = 0; i < 4; ++i){
    int nrow = i*16 + rr;
    int kc = cc*4;
    u16x4 o;
    o[0] = f2bf(tile[kc+0][nrow]);
    o[1] = f2bf(tile[kc+1][nrow]);
    o[2] = f2bf(tile[kc+2][nrow]);
    o[3] = f2bf(tile[kc+3][nrow]);
    *(u16x4*)(WT + (size_t)(n0+nrow)*K + k0 + kc) = o;
  }
}

// ---------------- RMSNorm: f32 in -> bf16 out ----------------
__global__ __launch_bounds__(256) void k_rmsnorm(const float* __restrict__ x,
                                                 const float* __restrict__ g,
                                                 u16* __restrict__ out){
  const int row = blockIdx.x; const int t = threadIdx.x;
  const float* xr = x + (size_t)row*D_MODEL;
  float4 v = *(const float4*)(xr + t*4);
  float ss = v.x*v.x + v.y*v.y + v.z*v.z + v.w*v.w;
  #pragma unroll
  for (int off = 1; off < 64; off <<= 1) ss += __shfl_xor(ss, off);
  __shared__ float wsum[4];
  if ((t & 63) == 0) wsum[t>>6] = ss;
  __syncthreads();
  float tot = wsum[0]+wsum[1]+wsum[2]+wsum[3];
  float sc = rsqrtf(tot * (1.0f/(float)D_MODEL) + 1e-6f);
  float4 gg = *(const float4*)(g + t*4);
  u16x4 o;
  o[0]=f2bf(v.x*sc*gg.x); o[1]=f2bf(v.y*sc*gg.y);
  o[2]=f2bf(v.z*sc*gg.z); o[3]=f2bf(v.w*sc*gg.w);
  *(u16x4*)(out + (size_t)row*D_MODEL + t*4) = o;
}

// ---------------- 256-tile GEMM, counted-vmcnt pipelined ----------------
template<int NREP, int MODE>
__global__ __launch_bounds__(512, 2) void k_gemm8(
    const u16* __restrict__ A, const u16* __restrict__ BT,
    u16* __restrict__ Cb, float* __restrict__ Cf,
    const float* __restrict__ resid, const u16* __restrict__ gate,
    int M, int N, int K, int nbx)
{
  __shared__ __align__(16) u16 lA[2][16384];
  __shared__ __align__(16) u16 lB[2][NREP*4096];
  const int t = threadIdx.x, wid = t >> 6, lane = t & 63, lr = lane & 15, lg = lane >> 4;
  const int wr = wid >> 2, wc = wid & 3;
  const int nwg = gridDim.x, bid = blockIdx.x;
  const int wg = (bid & 7) * (nwg >> 3) + (bid >> 3);   // bijective: nwg % 8 == 0
  const int bx = wg % nbx, by = wg / nbx;
  const int m0 = by * 256, n0 = bx * (NREP * 64);
  const int NT = K >> 6;

  f32x4 acc[8][NREP];
  #pragma unroll
  for (int i=0;i<8;++i)
    #pragma unroll
    for (int j=0;j<NREP;++j) acc[i][j] = (f32x4){0.f,0.f,0.f,0.f};

  #define STAGE_A(kt,p) { \
    _Pragma("unroll") \
    for (int i=0;i<4;++i){ \
      int ci = i*512 + t; int row = ci>>3, c = ci&7; \
      gload16(A + (size_t)(m0+row)*K + (kt)*64 + ((c ^ (row&7))*8), \
              (char*)lA[p] + i*8192 + wid*1024); } }
  #define STAGE_B(kt,p) { \
    _Pragma("unroll") \
    for (int i=0;i<NREP;++i){ \
      int ci = i*512 + t; int row = ci>>3, c = ci&7; \
      gload16(BT + (size_t)(n0+row)*K + (kt)*64 + ((c ^ (row&7))*8), \
              (char*)lB[p] + i*8192 + wid*1024); } }
  #define WAIT_L() { if constexpr (NREP==4) asm volatile("s_waitcnt vmcnt(8)" ::: "memory"); \
                     else                   asm volatile("s_waitcnt vmcnt(6)" ::: "memory"); }

  STAGE_A(0,0); STAGE_B(0,0);
  STAGE_A(1,1); STAGE_B(1,1);
  WAIT_L();
  __builtin_amdgcn_sched_barrier(0);
  __builtin_amdgcn_s_barrier();
  __builtin_amdgcn_sched_barrier(0);

  for (int kt = 0; kt < NT; ++kt){
    const int p = kt & 1;
    const u16* a = lA[p];
    const u16* b = lB[p];
    bf16x8 af[8][2], bfr[NREP][2];
    // ---- P1 ----
    #pragma unroll
    for (int mi=0;mi<4;++mi){
      int row = wr*128 + mi*16 + lr;
      af[mi][0] = *swzp(a, row,   lg);
      af[mi][1] = *swzp(a, row, 4+lg);
    }
    #pragma unroll
    for (int ni=0;ni<NREP/2;++ni){
      int row = wc*(NREP*16) + ni*16 + lr;
      bfr[ni][0] = *swzp(b, row,   lg);
      bfr[ni][1] = *swzp(b, row, 4+lg);
    }
    __builtin_amdgcn_s_setprio(1);
    #pragma unroll
    for (int mi=0;mi<4;++mi)
      #pragma unroll
      for (int ni=0;ni<NREP/2;++ni){
        acc[mi][ni] = __builtin_amdgcn_mfma_f32_16x16x32_bf16(af[mi][0], bfr[ni][0], acc[mi][ni], 0,0,0);
        acc[mi][ni] = __builtin_amdgcn_mfma_f32_16x16x32_bf16(af[mi][1], bfr[ni][1], acc[mi][ni], 0,0,0);
      }
    __builtin_amdgcn_s_setprio(0);
    // ---- P2 ----
    #pragma unroll
    for (int mi=4;mi<8;++mi){
      int row = wr*128 + mi*16 + lr;
      af[mi][0] = *swzp(a, row,   lg);
      af[mi][1] = *swzp(a, row, 4+lg);
    }
    #pragma unroll
    for (int ni=NREP/2;ni<NREP;++ni){
      int row = wc*(NREP*16) + ni*16 + lr;
      bfr[ni][0] = *swzp(b, row,   lg);
      bfr[ni][1] = *swzp(b, row, 4+lg);
    }
    __builtin_amdgcn_s_setprio(1);
    #pragma unroll
    for (int mi=4;mi<8;++mi)
      #pragma unroll
      for (int ni=0;ni<NREP/2;++ni){
        acc[mi][ni] = __builtin_amdgcn_mfma_f32_16x16x32_bf16(af[mi][0], bfr[ni][0], acc[mi][ni], 0,0,0);
        acc[mi][ni] = __builtin_amdgcn_mfma_f32_16x16x32_bf16(af[mi][1], bfr[ni][1], acc[mi][ni], 0,0,0);
      }
    __builtin_amdgcn_s_setprio(0);
    asm volatile("s_waitcnt lgkmcnt(0)" ::: "memory");
    __builtin_amdgcn_sched_barrier(0);
    __builtin_amdgcn_s_barrier();
    __builtin_amdgcn_sched_barrier(0);
    // ---- P3 ----
    if (kt + 2 < NT) STAGE_A(kt+2, p);
    __builtin_amdgcn_s_setprio(1);
    #pragma unroll
    for (int mi=0;mi<4;++mi)
      #pragma unroll
      for (int ni=NREP/2;ni<NREP;++ni){
        acc[mi][ni] = __builtin_amdgcn_mfma_f32_16x16x32_bf16(af[mi][0], bfr[ni][0], acc[mi][ni], 0,0,0);
        acc[mi][ni] = __builtin_amdgcn_mfma_f32_16x16x32_bf16(af[mi][1], bfr[ni][1], acc[mi][ni], 0,0,0);
      }
    __builtin_amdgcn_s_setprio(0);
    // ---- P4 ----
    if (kt + 2 < NT) STAGE_B(kt+2, p);
    __builtin_amdgcn_s_setprio(1);
    #pragma unroll
    for (int mi=4;mi<8;++mi)
      #pragma unroll
      for (int ni=NREP/2;ni<NREP;++ni){
        acc[mi][ni] = __builtin_amdgcn_mfma_f32_16x16x32_bf16(af[mi][0], bfr[ni][0], acc[mi][ni], 0,0,0);
        acc[mi][ni] = __builtin_amdgcn_mfma_f32_16x16x32_bf16(af[mi][1], bfr[ni][1], acc[mi][ni], 0,0,0);
      }
    __builtin_amdgcn_s_setprio(0);
    __builtin_amdgcn_sched_barrier(0);
    if (kt + 2 < NT) { WAIT_L(); }
    else             { asm volatile("s_waitcnt vmcnt(0)" ::: "memory"); }
    __builtin_amdgcn_s_barrier();
    __builtin_amdgcn_sched_barrier(0);
  }

  #pragma unroll
  for (int mi=0;mi<8;++mi)
    #pragma unroll
    for (int ni=0;ni<NREP;++ni){
      int mbase = m0 + wr*128 + mi*16 + lg*4;
      int n = n0 + wc*(NREP*16) + ni*16 + lr;
      #pragma unroll
      for (int r=0;r<4;++r){
        size_t idx = (size_t)(mbase + r)*N + n;
        float vv = acc[mi][ni][r];
        if (MODE == 0) Cb[idx] = f2bf(vv);
        else if (MODE == 1) Cf[idx] = resid[idx] + vv;
        else { float gt = bf2f(gate[idx]); float sg = gt / (1.f + __expf(-gt)); Cb[idx] = f2bf(sg * vv); }
      }
    }
  #undef STAGE_A
  #undef STAGE_B
  #undef WAIT_L
}

// ---------------- RoPE in-place on fused qkv (bf16), row stride 3072 ----------------
__global__ __launch_bounds__(256) void k_rope(u16* __restrict__ qkv,
                                              const float* __restrict__ cs,
                                              const float* __restrict__ sn){
  int tid = blockIdx.x*256 + threadIdx.x;
  int d = tid & 31, h = (tid >> 5) & 15, s = (tid >> 9) & 2047, b = tid >> 20;
  size_t base = ((size_t)(b*SEQ + s))*QKVW + h*HD;
  float c1 = cs[s*HD + d],      s1 = sn[s*HD + d];
  float c2 = cs[s*HD + d + 32], s2 = sn[s*HD + d + 32];
  float q1 = bf2f(qkv[base+d]), q2 = bf2f(qkv[base+d+32]);
  qkv[base+d]    = f2bf(q1*c1 - q2*s1);
  qkv[base+d+32] = f2bf(q2*c2 + q1*s2);
  size_t kb = base + 1024;
  float k1 = bf2f(qkv[kb+d]), k2 = bf2f(qkv[kb+d+32]);
  qkv[kb+d]    = f2bf(k1*c1 - k2*s1);
  qkv[kb+d+32] = f2bf(k2*c2 + k1*s2);
}

// ---------------- V transpose: qkv v-slice -> vt[(b*16+h)*64+d][S] ----------------
__global__ __launch_bounds__(256) void k_transpose_v(const u16* __restrict__ qkv,
                                                     u16* __restrict__ vt){
  const int s0 = blockIdx.x*64; const int bh = blockIdx.y;
  const int b = bh >> 4, h = bh & 15;
  __shared__ u16 tile[64][72];
  const int t = threadIdx.x;
  #pragma unroll
  for (int i=0;i<2;++i){
    int c = i*256 + t;
    int sr = c >> 3, ch = c & 7;
    u16x8 vv = *(const u16x8*)(qkv + (size_t)(b*SEQ + s0 + sr)*QKVW + 2048 + h*HD + ch*8);
    #pragma unroll
    for (int j=0;j<8;++j) tile[sr][ch*8+j] = vv[j];
  }
  __syncthreads();
  #pragma unroll
  for (int i=0;i<2;++i){
    int c = i*256 + t;
    int dr = c >> 3, ch = c & 7;
    u16x8 o;
    #pragma unroll
    for (int j=0;j<8;++j) o[j] = tile[ch*8+j][dr];
    *(u16x8*)(vt + (size_t)(bh*HD + dr)*SEQ + s0 + ch*8) = o;
  }
}

// ---------------- causal flash attention, swapped-operand 16x16 ----------------
// grid (64 bh, 32 qtiles heavy-first), block 256 = 4 waves x 16 q-rows.
// All MFMA layouts = verified 16x16x32 mappings (same as k_gemm8 / r3 k_attn).
// S^T = K·Q^T : D[m=kv][n=q], col=lane&15=q -> softmax per-lane scalar state,
// reduce only over lg-group (shfl_xor 16,32). O^T = V^T·P^T : col=q, rescale
// lane-local. P re-layout via per-wave LDS with explicit [q][kv] indices.
__global__ __launch_bounds__(256) void k_attn3(const u16* __restrict__ qkv,
                                               const u16* __restrict__ vt,
                                               u16* __restrict__ ctx){
  const int bh = blockIdx.x;
  const int qt = (int)gridDim.y - 1 - (int)blockIdx.y;   // 0..31, heavy first
  const int b = bh >> 4, h = bh & 15;
  const int t = threadIdx.x, wid = t >> 6, lane = t & 63;
  const int lr = lane & 15, lg = lane >> 4;
  __shared__ __align__(16) u16 kld[2][64*64];   // [kv][d] swizzled
  __shared__ __align__(16) u16 vld[2][64*64];   // [d][kv] swizzled
  __shared__ __align__(16) u16 pld[4][16][72];  // per-wave P[q][kv] (+pad, 144B rows)

  const int qw0 = qt*64 + wid*16;
  const int qg = qw0 + lr;
  const u16* qrow = qkv + (size_t)(b*SEQ + qg)*QKVW + h*HD;
  bf16x8 qf0 = *(const bf16x8*)(qrow + lg*8);        // B-frag: n=q(own row), k=d
  bf16x8 qf1 = *(const bf16x8*)(qrow + 32 + lg*8);

  f32x4 o[4];                                        // O^T d-tiles, col=q
  #pragma unroll
  for (int dt=0;dt<4;++dt) o[dt] = (f32x4){0.f,0.f,0.f,0.f};
  float m_run = -INFINITY, l_run = 0.f;
  const float SC2 = 0.125f * 1.4426950408889634f;    // exp2-domain scale

  const int nt = qt + 1;

  #define ASTAGE(it_, p_) { \
    const int kv0_ = (it_)*64; \
    _Pragma("unroll") \
    for (int i=0;i<2;++i){ \
      int ci = i*256 + t; int row = ci>>3, c = ci&7, cg = c ^ (row&7); \
      gload16(qkv + (size_t)(b*SEQ + kv0_ + row)*QKVW + 1024 + h*HD + cg*8, \
              (char*)kld[p_] + i*4096 + wid*1024); \
      gload16(vt + (size_t)(bh*HD + row)*SEQ + kv0_ + cg*8, \
              (char*)vld[p_] + i*4096 + wid*1024); \
    } }

  ASTAGE(0, 0);
  asm volatile("s_waitcnt vmcnt(0)" ::: "memory");
  __builtin_amdgcn_sched_barrier(0);
  __builtin_amdgcn_s_barrier();
  __builtin_amdgcn_sched_barrier(0);

  for (int it = 0; it < nt; ++it){
    const int p = it & 1;
    if (it + 1 < nt) ASTAGE(it+1, p^1);
    const int kv0 = it*64;
    // ---- QK^T: S^T[kv tile c][q], A=K rows kv, B=Q^T ----
    f32x4 s[4];
    #pragma unroll
    for (int c=0;c<4;++c) s[c] = (f32x4){0.f,0.f,0.f,0.f};
    #pragma unroll
    for (int c=0;c<4;++c){
      s[c] = __builtin_amdgcn_mfma_f32_16x16x32_bf16(*swzp(kld[p], c*16+lr,   lg), qf0, s[c], 0,0,0);
      s[c] = __builtin_amdgcn_mfma_f32_16x16x32_bf16(*swzp(kld[p], c*16+lr, 4+lg), qf1, s[c], 0,0,0);
    }
    // ---- scale + causal mask + per-lane softmax (reduce over lg only) ----
    const bool domask = (it == qt);
    float pm = -INFINITY;
    #pragma unroll
    for (int c=0;c<4;++c)
      #pragma unroll
      for (int r=0;r<4;++r){
        float v = s[c][r]*SC2;
        if (domask && (kv0 + c*16 + lg*4 + r > qg)) v = -INFINITY;
        s[c][r] = v;
        pm = fmaxf(pm, v);
      }
    pm = fmaxf(pm, __shfl_xor(pm, 16));
    pm = fmaxf(pm, __shfl_xor(pm, 32));
    float mnew = fmaxf(m_run, pm);
    float alpha = exp2f(fmaxf(m_run - mnew, -100.f));
    m_run = mnew;
    float lsum = 0.f;
    #pragma unroll
    for (int c=0;c<4;++c)
      #pragma unroll
      for (int r=0;r<4;++r){
        s[c][r] = exp2f(s[c][r] - mnew);
        lsum += s[c][r];
      }
    lsum += __shfl_xor(lsum, 16);
    lsum += __shfl_xor(lsum, 32);
    l_run = l_run*alpha + lsum;
    #pragma unroll
    for (int dt=0;dt<4;++dt)
      #pragma unroll
      for (int r=0;r<4;++r) o[dt][r] *= alpha;
    // ---- P -> per-wave LDS [q][kv] (explicit C/D indices) ----
    #pragma unroll
    for (int c=0;c<4;++c)
      #pragma unroll
      for (int r=0;r<4;++r)
        pld[wid][lr][c*16 + lg*4 + r] = f2bf(s[c][r]);
    // ---- PV: O^T += V^T·P^T ; B-frag = pld[q][ks*32 + lg*8 ..] ----
    bf16x8 pb0 = *(const bf16x8*)(&pld[wid][lr][lg*8]);
    bf16x8 pb1 = *(const bf16x8*)(&pld[wid][lr][32 + lg*8]);
    #pragma unroll
    for (int dt=0;dt<4;++dt){
      o[dt] = __builtin_amdgcn_mfma_f32_16x16x32_bf16(*swzp(vld[p], dt*16+lr,   lg), pb0, o[dt], 0,0,0);
      o[dt] = __builtin_amdgcn_mfma_f32_16x16x32_bf16(*swzp(vld[p], dt*16+lr, 4+lg), pb1, o[dt], 0,0,0);
    }
    asm volatile("s_waitcnt vmcnt(0)" ::: "memory");
    __builtin_amdgcn_sched_barrier(0);
    __builtin_amdgcn_s_barrier();
    __builtin_amdgcn_sched_barrier(0);
  }
  #undef ASTAGE

  const float inv = 1.f / l_run;
  u16* crow_out = ctx + (size_t)(b*SEQ + qg)*D_MODEL + h*HD;
  #pragma unroll
  for (int dt=0;dt<4;++dt){
    u16x4 st;
    #pragma unroll
    for (int r=0;r<4;++r) st[r] = f2bf(o[dt][r] * inv);
    *(u16x4*)(crow_out + dt*16 + lg*4) = st;
  }
}

extern "C" void kernel_launch(void* const* d_in, const int* in_sizes, int n_in,
                              void* d_out, int out_size, void* d_ws, size_t ws_size,
                              hipStream_t stream){
  const float* x  = (const float*)d_in[0];
  const float* rc = (const float*)d_in[1];
  const float* rs = (const float*)d_in[2];
  const float* g1 = (const float*)d_in[3];
  const float* g2 = (const float*)d_in[4];
  const float* wq = (const float*)d_in[5];
  const float* wk = (const float*)d_in[6];
  const float* wv = (const float*)d_in[7];
  const float* wo = (const float*)d_in[8];
  const float* wg = (const float*)d_in[9];
  const float* wu = (const float*)d_in[10];
  const float* wd = (const float*)d_in[11];
  float* out = (float*)d_out;

  char* ws = (char*)d_ws;
  const size_t MB = 1024*1024;
  u16* wqkvT = (u16*)(ws + 0);          // [3072][1024] bf16
  u16* woT   = (u16*)(ws + 6*MB);
  u16* wgT   = (u16*)(ws + 8*MB);
  u16* wuT   = (u16*)(ws + 16*MB);
  u16* wdT   = (u16*)(ws + 24*MB);
  float* x1  = (float*)(ws + 32*MB);
  u16* xn    = (u16*)(ws + 64*MB);      // xn -> ctx -> xn2 (sequential reuse)
  u16* qkv   = (u16*)(ws + 80*MB);      // [8192][3072]
  u16* vtb   = (u16*)(ws + 128*MB);
  u16* gb    = (u16*)(ws + 144*MB);     // [8192][4096] gate then h

  dim3 blk(256);
  k_transpose_w<<<dim3(16,16),blk,0,stream>>>(wq, wqkvT,             1024, 1024);
  k_transpose_w<<<dim3(16,16),blk,0,stream>>>(wk, wqkvT + 1024*1024, 1024, 1024);
  k_transpose_w<<<dim3(16,16),blk,0,stream>>>(wv, wqkvT + 2048*1024, 1024, 1024);
  k_transpose_w<<<dim3(16,16),blk,0,stream>>>(wo, woT, 1024, 1024);
  k_transpose_w<<<dim3(64,16),blk,0,stream>>>(wg, wgT, 1024, 4096);
  k_transpose_w<<<dim3(64,16),blk,0,stream>>>(wu, wuT, 1024, 4096);
  k_transpose_w<<<dim3(16,64),blk,0,stream>>>(wd, wdT, 4096, 1024);

  k_rmsnorm<<<dim3(NROWS),blk,0,stream>>>(x, g1, xn);

  k_gemm8<4,0><<<dim3(384),dim3(512),0,stream>>>(xn, wqkvT, qkv, nullptr, nullptr, nullptr,
                                                 NROWS, QKVW, 1024, 12);

  k_rope<<<dim3((BATCH*SEQ*NH*32)/256),blk,0,stream>>>(qkv, rc, rs);
  k_transpose_v<<<dim3(32,64),blk,0,stream>>>(qkv, vtb);
  k_attn3<<<dim3(64,32),blk,0,stream>>>(qkv, vtb, xn);

  k_gemm8<2,1><<<dim3(256),dim3(512),0,stream>>>(xn, woT, nullptr, x1, x, nullptr,
                                                 NROWS, 1024, 1024, 8);

  k_rmsnorm<<<dim3(NROWS),blk,0,stream>>>(x1, g2, xn);

  k_gemm8<4,0><<<dim3(512),dim3(512),0,stream>>>(xn, wgT, gb, nullptr, nullptr, nullptr,
                                                 NROWS, 4096, 1024, 16);
  k_gemm8<4,2><<<dim3(512),dim3(512),0,stream>>>(xn, wuT, gb, nullptr, nullptr, gb,
                                                 NROWS, 4096, 1024, 16);
  k_gemm8<2,1><<<dim3(256),dim3(512),0,stream>>>(gb, wdT, nullptr, out, x1, nullptr,
                                                 NROWS, 1024, 4096, 8);
}